// Round 17
// baseline (95.031 us; speedup 1.0000x reference)
//
#include <hip/hip_runtime.h>

#define Bn 64
#define Dn 128
#define Ln 512

typedef __attribute__((ext_vector_type(8))) _Float16 half8;
typedef __attribute__((ext_vector_type(4))) float f32x4;

__device__ __forceinline__ void cvt8h(const float* xs, half8& hi) {
#pragma unroll
  for (int j = 0; j < 8; ++j) hi[j] = (_Float16)xs[j];
}
__device__ __forceinline__ void gll16(const void* g, void* l) {
  __builtin_amdgcn_global_load_lds(
      (const __attribute__((address_space(1))) void*)g,
      (__attribute__((address_space(3))) void*)l, 16, 0, 0);
}

// ---- kz: Z[bh][m][d] = sum_e X2[m,b,e] WU[h,d,e]. 64-row tiles, grid 2048.
// Full 1-term f16 (A = X2 cvt, B = WU cvt direct from f32 — kw fused away).
// Epilogue: single-f16 frag-ordered zimg units. ----
__global__ __launch_bounds__(256, 3) void kz(const float* __restrict__ X2,
                                             const float* __restrict__ WU,
                                             _Float16* __restrict__ zimg) {
  __shared__ __align__(16) float zt[64 * 132];  // 33792 B
  int orig = blockIdx.x;
  int blk = (orig & 7) * 256 + (orig >> 3);  // XCD swizzle (2048 = 8*256)
  int h = blk & 3, mt6 = (blk >> 2) & 7, b = blk >> 5;
  int t = threadIdx.x, ln = t & 63, wv = t >> 6;
  int rg = wv >> 1, cb = wv & 1;
  int R0 = rg * 32;  // local row base in 64-row tile
  int eo = (ln >> 4) * 8;

  // A resident: X2 rows mt6*64 + R0 + mr*16 + (ln&15), single f16
  half8 ahf[2][4];
#pragma unroll
  for (int mr = 0; mr < 2; ++mr) {
    const float* rsrc =
        X2 + ((size_t)(mt6 * 64 + R0 + mr * 16 + (ln & 15)) * Bn + b) * Dn + eo;
#pragma unroll
    for (int ks = 0; ks < 4; ++ks) {
      float xs[8];
      *(float4*)xs = *(const float4*)(rsrc + ks * 32);
      *(float4*)(xs + 4) = *(const float4*)(rsrc + ks * 32 + 4);
      cvt8h(xs, ahf[mr][ks]);
    }
  }

  const f32x4 fz = {0.f, 0.f, 0.f, 0.f};
#pragma unroll
  for (int ph = 0; ph < 2; ++ph) {  // d cols = cb*64 + ph*32
    // B frags direct from WU (L2-hot): rows d, k = e
    half8 bhf[2][4];
#pragma unroll
    for (int nr = 0; nr < 2; ++nr) {
      int d = cb * 64 + ph * 32 + nr * 16 + (ln & 15);
      const float* wsrc = WU + ((size_t)h * Dn + d) * Dn + eo;
#pragma unroll
      for (int ks = 0; ks < 4; ++ks) {
        float xs[8];
        *(float4*)xs = *(const float4*)(wsrc + ks * 32);
        *(float4*)(xs + 4) = *(const float4*)(wsrc + ks * 32 + 4);
        cvt8h(xs, bhf[nr][ks]);
      }
    }
    f32x4 acc[2][2];
#pragma unroll
    for (int i = 0; i < 2; ++i) {
      acc[i][0] = fz;
      acc[i][1] = fz;
    }
#pragma unroll
    for (int ks = 0; ks < 4; ++ks)
#pragma unroll
      for (int mr = 0; mr < 2; ++mr) {
        acc[mr][0] = __builtin_amdgcn_mfma_f32_16x16x32_f16(ahf[mr][ks], bhf[0][ks], acc[mr][0], 0, 0, 0);
        acc[mr][1] = __builtin_amdgcn_mfma_f32_16x16x32_f16(ahf[mr][ks], bhf[1][ks], acc[mr][1], 0, 0, 0);
      }
#pragma unroll
    for (int mr = 0; mr < 2; ++mr) {
      int rb = R0 + mr * 16 + (ln >> 4) * 4;
#pragma unroll
      for (int nr = 0; nr < 2; ++nr) {
        int d = cb * 64 + ph * 32 + nr * 16 + (ln & 15);
#pragma unroll
        for (int j = 0; j < 4; ++j) zt[(rb + j) * 132 + d] = acc[mr][nr][j];
      }
    }
  }
  __syncthreads();
  // epilogue: zt -> single-f16 frag-ordered zimg units (16: 4 mgrp x 4 ks)
  int bh = b * 4 + h;
#pragma unroll
  for (int p = 0; p < 4; ++p) {
    int u = p * 4 + wv;  // mgl = u>>2, ksu = u&3
    int r = (u >> 2) * 16 + (ln & 15);
    int d = (u & 3) * 32 + eo;
    float xs[8];
    *(float4*)xs = *(const float4*)(zt + r * 132 + d);
    *(float4*)(xs + 4) = *(const float4*)(zt + r * 132 + d + 4);
    half8 hi;
    cvt8h(xs, hi);
    size_t ub = (((size_t)bh * 32 + mt6 * 4 + (u >> 2)) * 4 + (u & 3)) * 512 +
                (size_t)ln * 8;
    *(half8*)(zimg + ub) = hi;
  }
}

// ---- k1: per (b,h,rowhalf): 4 waves x 64 rows = 256 rows, ALL 512 cols.
// f16 1-term; 64-col chunks (8 phases x 64 MFMA), 16KB stage, gll dbuf. ----
__global__ __launch_bounds__(256, 2) void k1(const float* __restrict__ X1,
                                             const _Float16* __restrict__ zimg,
                                             const int* __restrict__ raw1,
                                             const int* __restrict__ raw2,
                                             float* __restrict__ s1,
                                             float* __restrict__ s2pp) {
  __shared__ __align__(16) char Bbuf[2][16384];
  __shared__ float m1f[256];
  __shared__ float m2f[512];
  __shared__ float cmbuf[4][512];

  int orig = blockIdx.x;
  int blk = (orig & 7) * 64 + (orig >> 3);  // XCD swizzle (512 = 8*64)
  int rh = blk & 1, h = (blk >> 1) & 3, b = blk >> 3;
  int bh = b * 4 + h;
  int t = threadIdx.x, ln = t & 63, wv = t >> 6;  // wv 0..3
  int R0 = rh * 256 + wv * 64;                    // global row base

  m1f[t] = (raw1[(size_t)(rh * 256 + t) * Bn + b] == 0) ? 1.0e4f : 0.0f;
  for (int i = t; i < 512; i += 256)
    m2f[i] = (raw2[(size_t)i * Bn + b] == 0) ? 1.0e4f : 0.0f;

  // chunk c: cols c*64 (4 cg-units); 8192 halves (16KB) linear at
  // (bh*32 + c*4)*2048. Per wave: 4 gll16 (unit wv + p*4).
#define STAGE(bb, c_)                                                    \
  {                                                                      \
    size_t ub = ((size_t)bh * 32 + (c_)*4) * 2048;                       \
    _Pragma("unroll") for (int p = 0; p < 4; ++p) {                      \
      gll16(zimg + ub + (size_t)(wv + p * 4) * 512 + (size_t)ln * 8,     \
            Bbuf[bb] + (wv + p * 4) * 1024);                             \
    }                                                                    \
  }

  STAGE(0, 0);

  // A resident: rows R0 + mr*16 + (ln&15), k = ks*32 + (ln>>4)*8, single f16
  half8 ahf[4][4];
  {
    int eo = (ln >> 4) * 8;
#pragma unroll
    for (int mr = 0; mr < 4; ++mr) {
      const float* rsrc =
          X1 + ((size_t)(R0 + mr * 16 + (ln & 15)) * Bn + b) * Dn + eo;
#pragma unroll
      for (int ks = 0; ks < 4; ++ks) {
        float xs[8];
        *(float4*)xs = *(const float4*)(rsrc + ks * 32);
        *(float4*)(xs + 4) = *(const float4*)(rsrc + ks * 32 + 4);
        cvt8h(xs, ahf[mr][ks]);
      }
    }
  }
  __syncthreads();  // stage(0) landed + masks ready

  float msub1[4][4];
#pragma unroll
  for (int mr = 0; mr < 4; ++mr)
#pragma unroll
    for (int j = 0; j < 4; ++j)
      msub1[mr][j] = m1f[wv * 64 + mr * 16 + (ln >> 4) * 4 + j];

  float rmrun[4][4];
#pragma unroll
  for (int i = 0; i < 4; ++i)
#pragma unroll
    for (int j = 0; j < 4; ++j) rmrun[i][j] = -3.0e38f;

  const f32x4 fz = {0.f, 0.f, 0.f, 0.f};
  int cur = 0;
  for (int c = 0; c < 8; ++c) {  // cols = c*64 .. +64
    if (c < 7) STAGE(cur ^ 1, c + 1);  // issue-early; ages under compute

    f32x4 acc[4][4];
#pragma unroll
    for (int i = 0; i < 4; ++i)
#pragma unroll
      for (int n = 0; n < 4; ++n) acc[i][n] = fz;
#pragma unroll
    for (int ks = 0; ks < 4; ++ks) {
      const char* base = Bbuf[cur] + ks * 1024 + ln * 16;
      half8 b0 = *(const half8*)base;
      half8 b1 = *(const half8*)(base + 4096);
      half8 b2 = *(const half8*)(base + 8192);
      half8 b3 = *(const half8*)(base + 12288);
#pragma unroll
      for (int mr = 0; mr < 4; ++mr) {
        acc[mr][0] = __builtin_amdgcn_mfma_f32_16x16x32_f16(ahf[mr][ks], b0, acc[mr][0], 0, 0, 0);
        acc[mr][1] = __builtin_amdgcn_mfma_f32_16x16x32_f16(ahf[mr][ks], b1, acc[mr][1], 0, 0, 0);
        acc[mr][2] = __builtin_amdgcn_mfma_f32_16x16x32_f16(ahf[mr][ks], b2, acc[mr][2], 0, 0, 0);
        acc[mr][3] = __builtin_amdgcn_mfma_f32_16x16x32_f16(ahf[mr][ks], b3, acc[mr][3], 0, 0, 0);
      }
    }
    // masked reductions
    float ms[4];
#pragma unroll
    for (int nr = 0; nr < 4; ++nr) ms[nr] = m2f[c * 64 + nr * 16 + (ln & 15)];
#pragma unroll
    for (int mr = 0; mr < 4; ++mr)
#pragma unroll
      for (int j = 0; j < 4; ++j) {
        float cc = fmaxf(fmaxf(acc[mr][0][j] - ms[0], acc[mr][1][j] - ms[1]),
                         fmaxf(acc[mr][2][j] - ms[2], acc[mr][3][j] - ms[3]));
        rmrun[mr][j] = fmaxf(rmrun[mr][j], cc);
      }
#pragma unroll
    for (int nr = 0; nr < 4; ++nr) {
      float v = -3.0e38f;
#pragma unroll
      for (int mr = 0; mr < 4; ++mr)
#pragma unroll
        for (int j = 0; j < 4; ++j) v = fmaxf(v, acc[mr][nr][j] - msub1[mr][j]);
      v = fmaxf(v, __shfl_xor(v, 16));
      v = fmaxf(v, __shfl_xor(v, 32));
      if (ln < 16) cmbuf[wv][c * 64 + nr * 16 + ln] = v;
    }
    __syncthreads();  // buf[cur] reads done; stage(cur^1) landed
    cur ^= 1;
  }
#undef STAGE

  // rowmax cross-lane + write (complete: all 512 cols seen)
#pragma unroll
  for (int off = 1; off < 16; off <<= 1)
#pragma unroll
    for (int mr = 0; mr < 4; ++mr)
#pragma unroll
      for (int j = 0; j < 4; ++j)
        rmrun[mr][j] = fmaxf(rmrun[mr][j], __shfl_xor(rmrun[mr][j], off));
  if ((ln & 15) == 0) {
    float* dst = s1 + (size_t)bh * 512 + R0 + (ln >> 4) * 4;
#pragma unroll
    for (int mr = 0; mr < 4; ++mr)
#pragma unroll
      for (int j = 0; j < 4; ++j) dst[mr * 16 + j] = rmrun[mr][j];
  }
  // colmax combine across 4 waves (partial: this rowhalf's 256 rows)
  for (int i = t; i < 512; i += 256) {
    float v = fmaxf(fmaxf(cmbuf[0][i], cmbuf[1][i]),
                    fmaxf(cmbuf[2][i], cmbuf[3][i]));
    s2pp[((size_t)bh * 2 + rh) * 512 + i] = v;
  }
}

// ---- k2: (side,b,lq): wave h = tanh+softmax; partial readout over l-quarter
__global__ __launch_bounds__(256) void k2(const float* __restrict__ s1,
                                          const float* __restrict__ s2pp,
                                          const float* __restrict__ X1,
                                          const float* __restrict__ X2,
                                          float* __restrict__ out,
                                          float* __restrict__ rws4) {
  __shared__ float aL[4][512];
  __shared__ f32x4 redv[4][8][32];
  int blk = blockIdx.x;  // 512
  int side = blk >> 8, b = (blk >> 2) & 63, lq = blk & 3;
  int t = threadIdx.x, ln = t & 63, h = t >> 6;
  int bh = b * 4 + h;
  int base = ln * 8;

  float vals[8];
  if (side == 0) {
    const float* p = s1 + (size_t)bh * 512 + base;
    float4 va = *(const float4*)p;
    float4 vb = *(const float4*)(p + 4);
    vals[0] = va.x; vals[1] = va.y; vals[2] = va.z; vals[3] = va.w;
    vals[4] = vb.x; vals[5] = vb.y; vals[6] = vb.z; vals[7] = vb.w;
  } else {
    const float* p0 = s2pp + (size_t)bh * 1024 + base;
    float4 va0 = *(const float4*)p0;
    float4 va1 = *(const float4*)(p0 + 4);
    float4 vb0 = *(const float4*)(p0 + 512);
    float4 vb1 = *(const float4*)(p0 + 516);
    vals[0] = fmaxf(va0.x, vb0.x); vals[1] = fmaxf(va0.y, vb0.y);
    vals[2] = fmaxf(va0.z, vb0.z); vals[3] = fmaxf(va0.w, vb0.w);
    vals[4] = fmaxf(va1.x, vb1.x); vals[5] = fmaxf(va1.y, vb1.y);
    vals[6] = fmaxf(va1.z, vb1.z); vals[7] = fmaxf(va1.w, vb1.w);
  }
#pragma unroll
  for (int q = 0; q < 8; ++q) vals[q] = tanhf(vals[q]);
  float mx = vals[0];
#pragma unroll
  for (int q = 1; q < 8; ++q) mx = fmaxf(mx, vals[q]);
#pragma unroll
  for (int off = 1; off < 64; off <<= 1) mx = fmaxf(mx, __shfl_xor(mx, off));
  float s = 0.0f;
#pragma unroll
  for (int q = 0; q < 8; ++q) {
    vals[q] = expf(vals[q] - mx);
    s += vals[q];
  }
#pragma unroll
  for (int off = 1; off < 64; off <<= 1) s += __shfl_xor(s, off);
  float inv = 1.0f / s;
#pragma unroll
  for (int q = 0; q < 8; ++q) vals[q] *= inv;

  if (lq == 0) {
    int aoff = (side == 0 ? 16384 : 147456) + bh * 512 + base;
    *(float4*)(out + aoff) = make_float4(vals[0], vals[1], vals[2], vals[3]);
    *(float4*)(out + aoff + 4) = make_float4(vals[4], vals[5], vals[6], vals[7]);
  }
  *(float4*)(&aL[h][base]) = make_float4(vals[0], vals[1], vals[2], vals[3]);
  *(float4*)(&aL[h][base + 4]) = make_float4(vals[4], vals[5], vals[6], vals[7]);
  __syncthreads();

  // partial readout over l in [lq*128, +128)
  const float4* X4 = (const float4*)(side == 0 ? X1 : X2);
  int q = t & 31, lg = t >> 5;
  f32x4 av[4];
  const f32x4 fz = {0.f, 0.f, 0.f, 0.f};
#pragma unroll
  for (int hh = 0; hh < 4; ++hh) av[hh] = fz;
#pragma unroll 4
  for (int l = lq * 128 + lg; l < lq * 128 + 128; l += 8) {
    float4 xv = X4[((size_t)l * Bn + b) * 32 + q];
#pragma unroll
    for (int hh = 0; hh < 4; ++hh) {
      float w = aL[hh][l];
      av[hh][0] += w * xv.x;
      av[hh][1] += w * xv.y;
      av[hh][2] += w * xv.z;
      av[hh][3] += w * xv.w;
    }
  }
#pragma unroll
  for (int hh = 0; hh < 4; ++hh) redv[hh][lg][q] = av[hh];
  __syncthreads();
  if (t < 128) {
    int d = t;
#pragma unroll
    for (int hh = 0; hh < 4; ++hh) {
      float s2v = 0.0f;
#pragma unroll
      for (int g = 0; g < 8; ++g) s2v += ((const float*)&redv[hh][g][d >> 2])[d & 3];
      rws4[(((size_t)(side * 64 + b) * 4 + hh) * 4 + lq) * 128 + d] = s2v;
    }
  }
}

// ---- k3: combine hops (sums lq partials) ----
__global__ __launch_bounds__(128) void k3(const float* __restrict__ rws4,
                                          const float* __restrict__ Wipm,
                                          float* __restrict__ out) {
  int b = blockIdx.x, t = threadIdx.x;  // t = d
  __shared__ float r2l[4][128];
  __shared__ float tsum[2][4];
  float r1h[4], r2h[4];
#pragma unroll
  for (int h = 0; h < 4; ++h) {
    float a0 = 0.f, a1 = 0.f;
#pragma unroll
    for (int lq = 0; lq < 4; ++lq) {
      a0 += rws4[(((size_t)b * 4 + h) * 4 + lq) * 128 + t];
      a1 += rws4[(((size_t)(64 + b) * 4 + h) * 4 + lq) * 128 + t];
    }
    r1h[h] = a0;
    r2h[h] = a1;
    r2l[h][t] = a1;
  }
  __syncthreads();
  float p[4] = {0, 0, 0, 0};
  for (int e = 0; e < 128; ++e) {
    float w = Wipm[t * 128 + e];
#pragma unroll
    for (int h = 0; h < 4; ++h) p[h] += w * r2l[h][e];
  }
#pragma unroll
  for (int h = 0; h < 4; ++h) p[h] *= r1h[h];
#pragma unroll
  for (int off = 1; off < 64; off <<= 1)
#pragma unroll
    for (int h = 0; h < 4; ++h) p[h] += __shfl_xor(p[h], off);
  if ((t & 63) == 0)
#pragma unroll
    for (int h = 0; h < 4; ++h) tsum[t >> 6][h] = p[h];
  __syncthreads();
  float ad[4], mx = -3.0e38f;
#pragma unroll
  for (int h = 0; h < 4; ++h) {
    float v = tanhf(tsum[0][h] + tsum[1][h]);
    ad[h] = v;
    mx = fmaxf(mx, v);
  }
  float s = 0.0f;
#pragma unroll
  for (int h = 0; h < 4; ++h) { ad[h] = expf(ad[h] - mx); s += ad[h]; }
  float inv = 1.0f / s;
#pragma unroll
  for (int h = 0; h < 4; ++h) ad[h] *= inv;
  if (t < 4) out[278528 + b * 4 + t] = ad[t];
  float f1 = 0.0f, f2 = 0.0f;
#pragma unroll
  for (int h = 0; h < 4; ++h) { f1 += ad[h] * r1h[h]; f2 += ad[h] * r2h[h]; }
  out[b * 128 + t] = f1;
  out[8192 + b * 128 + t] = f2;
}

extern "C" void kernel_launch(void* const* d_in, const int* in_sizes, int n_in,
                              void* d_out, int out_size, void* d_ws,
                              size_t ws_size, hipStream_t stream) {
  (void)in_sizes; (void)n_in; (void)out_size; (void)ws_size;
  const float* x1 = (const float*)d_in[0];
  const float* x2 = (const float*)d_in[1];
  const int* raw1 = (const int*)d_in[2];
  const int* raw2 = (const int*)d_in[3];
  const float* wu = (const float*)d_in[4];
  const float* wipm = (const float*)d_in[5];
  float* out = (float*)d_out;
  char* w = (char*)d_ws;
  _Float16* zimg = (_Float16*)w;                 // 32 MiB (64 MiB slot)
  float* s1 = (float*)(w + 67633152);            // 512 KiB [bh][512]
  float* s2pp = (float*)(w + 68157440);          // 1 MiB [bh][rh][512]
  float* rws4 = (float*)(w + 69206016);          // 1 MiB

  kz<<<2048, 256, 0, stream>>>(x2, wu, zimg);
  k1<<<512, 256, 0, stream>>>(x1, zimg, raw1, raw2, s1, s2pp);
  k2<<<512, 256, 0, stream>>>(s1, s2pp, x1, x2, out, rws4);
  k3<<<64, 128, 0, stream>>>(rws4, wipm, out);
}

// Round 18
// 77.042 us; speedup vs baseline: 1.2335x; 1.2335x over previous
//
#include <hip/hip_runtime.h>

#define Bn 64
#define Dn 128
#define Ln 512

typedef __attribute__((ext_vector_type(8))) _Float16 half8;
typedef __attribute__((ext_vector_type(4))) float f32x4;

__device__ __forceinline__ void cvt8h(const float* xs, half8& hi) {
#pragma unroll
  for (int j = 0; j < 8; ++j) hi[j] = (_Float16)xs[j];
}
__device__ __forceinline__ void gll16(const void* g, void* l) {
  __builtin_amdgcn_global_load_lds(
      (const __attribute__((address_space(1))) void*)g,
      (__attribute__((address_space(3))) void*)l, 16, 0, 0);
}

// ---- kw: W_U -> frag-ordered single-f16 image (coalesced source for kz) ----
__global__ __launch_bounds__(256) void kw(const float* __restrict__ WU,
                                          _Float16* __restrict__ wimg) {
  int blk = blockIdx.x;  // 32: h = blk>>3, dgrp = blk&7
  int t = threadIdx.x, ln = t & 63, ks = t >> 6;
  int h = blk >> 3, dgrp = blk & 7;
  int d = dgrp * 16 + (ln & 15), e = ks * 32 + (ln >> 4) * 8;
  const float* src = WU + ((size_t)h * Dn + d) * Dn + e;
  float xs[8];
  *(float4*)xs = *(const float4*)src;
  *(float4*)(xs + 4) = *(const float4*)(src + 4);
  half8 hi;
  cvt8h(xs, hi);
  size_t u = (size_t)((h * 8 + dgrp) * 4 + ks) * 512 + (size_t)ln * 8;
  *(half8*)(wimg + u) = hi;
}

// ---- kz: Z[bh][m][d] = sum_e X2[m,b,e] WU[h,d,e]. 64-row tiles, grid 2048.
// 1-term f16 both sides (A = X2 cvt, B = wimg coalesced). Single-f16 zimg. ----
__global__ __launch_bounds__(256, 3) void kz(const float* __restrict__ X2,
                                             const _Float16* __restrict__ wimg,
                                             _Float16* __restrict__ zimg) {
  __shared__ __align__(16) float zt[64 * 132];  // 33792 B
  int orig = blockIdx.x;
  int blk = (orig & 7) * 256 + (orig >> 3);  // XCD swizzle (2048 = 8*256)
  int h = blk & 3, mt6 = (blk >> 2) & 7, b = blk >> 5;
  int t = threadIdx.x, ln = t & 63, wv = t >> 6;
  int rg = wv >> 1, cb = wv & 1;
  int R0 = rg * 32;  // local row base in 64-row tile
  int eo = (ln >> 4) * 8;

  // A resident: X2 rows mt6*64 + R0 + mr*16 + (ln&15), single f16
  half8 ahf[2][4];
#pragma unroll
  for (int mr = 0; mr < 2; ++mr) {
    const float* rsrc =
        X2 + ((size_t)(mt6 * 64 + R0 + mr * 16 + (ln & 15)) * Bn + b) * Dn + eo;
#pragma unroll
    for (int ks = 0; ks < 4; ++ks) {
      float xs[8];
      *(float4*)xs = *(const float4*)(rsrc + ks * 32);
      *(float4*)(xs + 4) = *(const float4*)(rsrc + ks * 32 + 4);
      cvt8h(xs, ahf[mr][ks]);
    }
  }

  const f32x4 fz = {0.f, 0.f, 0.f, 0.f};
#pragma unroll
  for (int ph = 0; ph < 2; ++ph) {  // d cols = cb*64 + ph*32
    f32x4 acc[2][2];
#pragma unroll
    for (int i = 0; i < 2; ++i) {
      acc[i][0] = fz;
      acc[i][1] = fz;
    }
    int dg0 = cb * 4 + ph * 2;
#pragma unroll
    for (int ks = 0; ks < 4; ++ks) {
      const _Float16* ub =
          wimg + (size_t)((h * 8 + dg0) * 4 + ks) * 512 + (size_t)ln * 8;
      half8 b0 = *(const half8*)ub;
      half8 b1 = *(const half8*)(ub + 2048);  // next dgrp unit
#pragma unroll
      for (int mr = 0; mr < 2; ++mr) {
        acc[mr][0] = __builtin_amdgcn_mfma_f32_16x16x32_f16(ahf[mr][ks], b0, acc[mr][0], 0, 0, 0);
        acc[mr][1] = __builtin_amdgcn_mfma_f32_16x16x32_f16(ahf[mr][ks], b1, acc[mr][1], 0, 0, 0);
      }
    }
#pragma unroll
    for (int mr = 0; mr < 2; ++mr) {
      int rb = R0 + mr * 16 + (ln >> 4) * 4;
#pragma unroll
      for (int nr = 0; nr < 2; ++nr) {
        int d = cb * 64 + ph * 32 + nr * 16 + (ln & 15);
#pragma unroll
        for (int j = 0; j < 4; ++j) zt[(rb + j) * 132 + d] = acc[mr][nr][j];
      }
    }
  }
  __syncthreads();
  // epilogue: zt -> single-f16 frag-ordered zimg units (16: 4 mgrp x 4 ks)
  int bh = b * 4 + h;
#pragma unroll
  for (int p = 0; p < 4; ++p) {
    int u = p * 4 + wv;  // mgl = u>>2, ksu = u&3
    int r = (u >> 2) * 16 + (ln & 15);
    int d = (u & 3) * 32 + eo;
    float xs[8];
    *(float4*)xs = *(const float4*)(zt + r * 132 + d);
    *(float4*)(xs + 4) = *(const float4*)(zt + r * 132 + d + 4);
    half8 hi;
    cvt8h(xs, hi);
    size_t ub = (((size_t)bh * 32 + mt6 * 4 + (u >> 2)) * 4 + (u & 3)) * 512 +
                (size_t)ln * 8;
    *(half8*)(zimg + ub) = hi;
  }
}

// ---- k1: per (b,h,rowhalf): 4 waves x 64 rows = 256 rows, ALL 512 cols.
// f16 1-term; 64-col chunks (8 phases x 64 MFMA), 16KB stage, gll dbuf. ----
__global__ __launch_bounds__(256, 2) void k1(const float* __restrict__ X1,
                                             const _Float16* __restrict__ zimg,
                                             const int* __restrict__ raw1,
                                             const int* __restrict__ raw2,
                                             float* __restrict__ s1,
                                             float* __restrict__ s2pp) {
  __shared__ __align__(16) char Bbuf[2][16384];
  __shared__ float m1f[256];
  __shared__ float m2f[512];
  __shared__ float cmbuf[4][512];

  int orig = blockIdx.x;
  int blk = (orig & 7) * 64 + (orig >> 3);  // XCD swizzle (512 = 8*64)
  int rh = blk & 1, h = (blk >> 1) & 3, b = blk >> 3;
  int bh = b * 4 + h;
  int t = threadIdx.x, ln = t & 63, wv = t >> 6;  // wv 0..3
  int R0 = rh * 256 + wv * 64;                    // global row base

  m1f[t] = (raw1[(size_t)(rh * 256 + t) * Bn + b] == 0) ? 1.0e4f : 0.0f;
  for (int i = t; i < 512; i += 256)
    m2f[i] = (raw2[(size_t)i * Bn + b] == 0) ? 1.0e4f : 0.0f;

  // chunk c: cols c*64 (4 cg-units); 8192 halves (16KB) linear at
  // (bh*32 + c*4)*2048. Per wave: 4 gll16 (unit wv + p*4).
#define STAGE(bb, c_)                                                    \
  {                                                                      \
    size_t ub = ((size_t)bh * 32 + (c_)*4) * 2048;                       \
    _Pragma("unroll") for (int p = 0; p < 4; ++p) {                      \
      gll16(zimg + ub + (size_t)(wv + p * 4) * 512 + (size_t)ln * 8,     \
            Bbuf[bb] + (wv + p * 4) * 1024);                             \
    }                                                                    \
  }

  STAGE(0, 0);

  // A resident: rows R0 + mr*16 + (ln&15), k = ks*32 + (ln>>4)*8, single f16
  half8 ahf[4][4];
  {
    int eo = (ln >> 4) * 8;
#pragma unroll
    for (int mr = 0; mr < 4; ++mr) {
      const float* rsrc =
          X1 + ((size_t)(R0 + mr * 16 + (ln & 15)) * Bn + b) * Dn + eo;
#pragma unroll
      for (int ks = 0; ks < 4; ++ks) {
        float xs[8];
        *(float4*)xs = *(const float4*)(rsrc + ks * 32);
        *(float4*)(xs + 4) = *(const float4*)(rsrc + ks * 32 + 4);
        cvt8h(xs, ahf[mr][ks]);
      }
    }
  }
  __syncthreads();  // stage(0) landed + masks ready

  float msub1[4][4];
#pragma unroll
  for (int mr = 0; mr < 4; ++mr)
#pragma unroll
    for (int j = 0; j < 4; ++j)
      msub1[mr][j] = m1f[wv * 64 + mr * 16 + (ln >> 4) * 4 + j];

  float rmrun[4][4];
#pragma unroll
  for (int i = 0; i < 4; ++i)
#pragma unroll
    for (int j = 0; j < 4; ++j) rmrun[i][j] = -3.0e38f;

  const f32x4 fz = {0.f, 0.f, 0.f, 0.f};
  int cur = 0;
  for (int c = 0; c < 8; ++c) {  // cols = c*64 .. +64
    if (c < 7) STAGE(cur ^ 1, c + 1);  // issue-early; ages under compute

    f32x4 acc[4][4];
#pragma unroll
    for (int i = 0; i < 4; ++i)
#pragma unroll
      for (int n = 0; n < 4; ++n) acc[i][n] = fz;
#pragma unroll
    for (int ks = 0; ks < 4; ++ks) {
      const char* base = Bbuf[cur] + ks * 1024 + ln * 16;
      half8 b0 = *(const half8*)base;
      half8 b1 = *(const half8*)(base + 4096);
      half8 b2 = *(const half8*)(base + 8192);
      half8 b3 = *(const half8*)(base + 12288);
#pragma unroll
      for (int mr = 0; mr < 4; ++mr) {
        acc[mr][0] = __builtin_amdgcn_mfma_f32_16x16x32_f16(ahf[mr][ks], b0, acc[mr][0], 0, 0, 0);
        acc[mr][1] = __builtin_amdgcn_mfma_f32_16x16x32_f16(ahf[mr][ks], b1, acc[mr][1], 0, 0, 0);
        acc[mr][2] = __builtin_amdgcn_mfma_f32_16x16x32_f16(ahf[mr][ks], b2, acc[mr][2], 0, 0, 0);
        acc[mr][3] = __builtin_amdgcn_mfma_f32_16x16x32_f16(ahf[mr][ks], b3, acc[mr][3], 0, 0, 0);
      }
    }
    // masked reductions
    float ms[4];
#pragma unroll
    for (int nr = 0; nr < 4; ++nr) ms[nr] = m2f[c * 64 + nr * 16 + (ln & 15)];
#pragma unroll
    for (int mr = 0; mr < 4; ++mr)
#pragma unroll
      for (int j = 0; j < 4; ++j) {
        float cc = fmaxf(fmaxf(acc[mr][0][j] - ms[0], acc[mr][1][j] - ms[1]),
                         fmaxf(acc[mr][2][j] - ms[2], acc[mr][3][j] - ms[3]));
        rmrun[mr][j] = fmaxf(rmrun[mr][j], cc);
      }
#pragma unroll
    for (int nr = 0; nr < 4; ++nr) {
      float v = -3.0e38f;
#pragma unroll
      for (int mr = 0; mr < 4; ++mr)
#pragma unroll
        for (int j = 0; j < 4; ++j) v = fmaxf(v, acc[mr][nr][j] - msub1[mr][j]);
      v = fmaxf(v, __shfl_xor(v, 16));
      v = fmaxf(v, __shfl_xor(v, 32));
      if (ln < 16) cmbuf[wv][c * 64 + nr * 16 + ln] = v;
    }
    __syncthreads();  // buf[cur] reads done; stage(cur^1) landed
    cur ^= 1;
  }
#undef STAGE

  // rowmax cross-lane + write (complete: all 512 cols seen)
#pragma unroll
  for (int off = 1; off < 16; off <<= 1)
#pragma unroll
    for (int mr = 0; mr < 4; ++mr)
#pragma unroll
      for (int j = 0; j < 4; ++j)
        rmrun[mr][j] = fmaxf(rmrun[mr][j], __shfl_xor(rmrun[mr][j], off));
  if ((ln & 15) == 0) {
    float* dst = s1 + (size_t)bh * 512 + R0 + (ln >> 4) * 4;
#pragma unroll
    for (int mr = 0; mr < 4; ++mr)
#pragma unroll
      for (int j = 0; j < 4; ++j) dst[mr * 16 + j] = rmrun[mr][j];
  }
  // colmax combine across 4 waves (partial: this rowhalf's 256 rows)
  for (int i = t; i < 512; i += 256) {
    float v = fmaxf(fmaxf(cmbuf[0][i], cmbuf[1][i]),
                    fmaxf(cmbuf[2][i], cmbuf[3][i]));
    s2pp[((size_t)bh * 2 + rh) * 512 + i] = v;
  }
}

// ---- k2: (side,b,lq): wave h = tanh+softmax; partial readout over l-quarter
__global__ __launch_bounds__(256) void k2(const float* __restrict__ s1,
                                          const float* __restrict__ s2pp,
                                          const float* __restrict__ X1,
                                          const float* __restrict__ X2,
                                          float* __restrict__ out,
                                          float* __restrict__ rws4) {
  __shared__ float aL[4][512];
  __shared__ f32x4 redv[4][8][32];
  int blk = blockIdx.x;  // 512
  int side = blk >> 8, b = (blk >> 2) & 63, lq = blk & 3;
  int t = threadIdx.x, ln = t & 63, h = t >> 6;
  int bh = b * 4 + h;
  int base = ln * 8;

  float vals[8];
  if (side == 0) {
    const float* p = s1 + (size_t)bh * 512 + base;
    float4 va = *(const float4*)p;
    float4 vb = *(const float4*)(p + 4);
    vals[0] = va.x; vals[1] = va.y; vals[2] = va.z; vals[3] = va.w;
    vals[4] = vb.x; vals[5] = vb.y; vals[6] = vb.z; vals[7] = vb.w;
  } else {
    const float* p0 = s2pp + (size_t)bh * 1024 + base;
    float4 va0 = *(const float4*)p0;
    float4 va1 = *(const float4*)(p0 + 4);
    float4 vb0 = *(const float4*)(p0 + 512);
    float4 vb1 = *(const float4*)(p0 + 516);
    vals[0] = fmaxf(va0.x, vb0.x); vals[1] = fmaxf(va0.y, vb0.y);
    vals[2] = fmaxf(va0.z, vb0.z); vals[3] = fmaxf(va0.w, vb0.w);
    vals[4] = fmaxf(va1.x, vb1.x); vals[5] = fmaxf(va1.y, vb1.y);
    vals[6] = fmaxf(va1.z, vb1.z); vals[7] = fmaxf(va1.w, vb1.w);
  }
#pragma unroll
  for (int q = 0; q < 8; ++q) vals[q] = tanhf(vals[q]);
  float mx = vals[0];
#pragma unroll
  for (int q = 1; q < 8; ++q) mx = fmaxf(mx, vals[q]);
#pragma unroll
  for (int off = 1; off < 64; off <<= 1) mx = fmaxf(mx, __shfl_xor(mx, off));
  float s = 0.0f;
#pragma unroll
  for (int q = 0; q < 8; ++q) {
    vals[q] = expf(vals[q] - mx);
    s += vals[q];
  }
#pragma unroll
  for (int off = 1; off < 64; off <<= 1) s += __shfl_xor(s, off);
  float inv = 1.0f / s;
#pragma unroll
  for (int q = 0; q < 8; ++q) vals[q] *= inv;

  if (lq == 0) {
    int aoff = (side == 0 ? 16384 : 147456) + bh * 512 + base;
    *(float4*)(out + aoff) = make_float4(vals[0], vals[1], vals[2], vals[3]);
    *(float4*)(out + aoff + 4) = make_float4(vals[4], vals[5], vals[6], vals[7]);
  }
  *(float4*)(&aL[h][base]) = make_float4(vals[0], vals[1], vals[2], vals[3]);
  *(float4*)(&aL[h][base + 4]) = make_float4(vals[4], vals[5], vals[6], vals[7]);
  __syncthreads();

  // partial readout over l in [lq*128, +128)
  const float4* X4 = (const float4*)(side == 0 ? X1 : X2);
  int q = t & 31, lg = t >> 5;
  f32x4 av[4];
  const f32x4 fz = {0.f, 0.f, 0.f, 0.f};
#pragma unroll
  for (int hh = 0; hh < 4; ++hh) av[hh] = fz;
#pragma unroll 4
  for (int l = lq * 128 + lg; l < lq * 128 + 128; l += 8) {
    float4 xv = X4[((size_t)l * Bn + b) * 32 + q];
#pragma unroll
    for (int hh = 0; hh < 4; ++hh) {
      float w = aL[hh][l];
      av[hh][0] += w * xv.x;
      av[hh][1] += w * xv.y;
      av[hh][2] += w * xv.z;
      av[hh][3] += w * xv.w;
    }
  }
#pragma unroll
  for (int hh = 0; hh < 4; ++hh) redv[hh][lg][q] = av[hh];
  __syncthreads();
  if (t < 128) {
    int d = t;
#pragma unroll
    for (int hh = 0; hh < 4; ++hh) {
      float s2v = 0.0f;
#pragma unroll
      for (int g = 0; g < 8; ++g) s2v += ((const float*)&redv[hh][g][d >> 2])[d & 3];
      rws4[(((size_t)(side * 64 + b) * 4 + hh) * 4 + lq) * 128 + d] = s2v;
    }
  }
}

// ---- k3: combine hops (sums lq partials) ----
__global__ __launch_bounds__(128) void k3(const float* __restrict__ rws4,
                                          const float* __restrict__ Wipm,
                                          float* __restrict__ out) {
  int b = blockIdx.x, t = threadIdx.x;  // t = d
  __shared__ float r2l[4][128];
  __shared__ float tsum[2][4];
  float r1h[4], r2h[4];
#pragma unroll
  for (int h = 0; h < 4; ++h) {
    float a0 = 0.f, a1 = 0.f;
#pragma unroll
    for (int lq = 0; lq < 4; ++lq) {
      a0 += rws4[(((size_t)b * 4 + h) * 4 + lq) * 128 + t];
      a1 += rws4[(((size_t)(64 + b) * 4 + h) * 4 + lq) * 128 + t];
    }
    r1h[h] = a0;
    r2h[h] = a1;
    r2l[h][t] = a1;
  }
  __syncthreads();
  float p[4] = {0, 0, 0, 0};
  for (int e = 0; e < 128; ++e) {
    float w = Wipm[t * 128 + e];
#pragma unroll
    for (int h = 0; h < 4; ++h) p[h] += w * r2l[h][e];
  }
#pragma unroll
  for (int h = 0; h < 4; ++h) p[h] *= r1h[h];
#pragma unroll
  for (int off = 1; off < 64; off <<= 1)
#pragma unroll
    for (int h = 0; h < 4; ++h) p[h] += __shfl_xor(p[h], off);
  if ((t & 63) == 0)
#pragma unroll
    for (int h = 0; h < 4; ++h) tsum[t >> 6][h] = p[h];
  __syncthreads();
  float ad[4], mx = -3.0e38f;
#pragma unroll
  for (int h = 0; h < 4; ++h) {
    float v = tanhf(tsum[0][h] + tsum[1][h]);
    ad[h] = v;
    mx = fmaxf(mx, v);
  }
  float s = 0.0f;
#pragma unroll
  for (int h = 0; h < 4; ++h) { ad[h] = expf(ad[h] - mx); s += ad[h]; }
  float inv = 1.0f / s;
#pragma unroll
  for (int h = 0; h < 4; ++h) ad[h] *= inv;
  if (t < 4) out[278528 + b * 4 + t] = ad[t];
  float f1 = 0.0f, f2 = 0.0f;
#pragma unroll
  for (int h = 0; h < 4; ++h) { f1 += ad[h] * r1h[h]; f2 += ad[h] * r2h[h]; }
  out[b * 128 + t] = f1;
  out[8192 + b * 128 + t] = f2;
}

extern "C" void kernel_launch(void* const* d_in, const int* in_sizes, int n_in,
                              void* d_out, int out_size, void* d_ws,
                              size_t ws_size, hipStream_t stream) {
  (void)in_sizes; (void)n_in; (void)out_size; (void)ws_size;
  const float* x1 = (const float*)d_in[0];
  const float* x2 = (const float*)d_in[1];
  const int* raw1 = (const int*)d_in[2];
  const int* raw2 = (const int*)d_in[3];
  const float* wu = (const float*)d_in[4];
  const float* wipm = (const float*)d_in[5];
  float* out = (float*)d_out;
  char* w = (char*)d_ws;
  _Float16* zimg = (_Float16*)w;                 // 32 MiB (64 MiB slot)
  _Float16* wimg = (_Float16*)(w + 67108864);    // 128 KiB
  float* s1 = (float*)(w + 67633152);            // 512 KiB [bh][512]
  float* s2pp = (float*)(w + 68157440);          // 1 MiB [bh][rh][512]
  float* rws4 = (float*)(w + 69206016);          // 1 MiB

  kw<<<32, 256, 0, stream>>>(wu, wimg);
  kz<<<2048, 256, 0, stream>>>(x2, wimg, zimg);
  k1<<<512, 256, 0, stream>>>(x1, zimg, raw1, raw2, s1, s2pp);
  k2<<<512, 256, 0, stream>>>(s1, s2pp, x1, x2, out, rws4);
  k3<<<64, 128, 0, stream>>>(rws4, wipm, out);
}

// Round 19
// 68.129 us; speedup vs baseline: 1.3949x; 1.1308x over previous
//
#include <hip/hip_runtime.h>

#define Bn 64
#define Dn 128
#define Ln 512

typedef __attribute__((ext_vector_type(8))) _Float16 half8;
typedef __attribute__((ext_vector_type(4))) float f32x4;

__device__ __forceinline__ void cvt8h(const float* xs, half8& hi) {
#pragma unroll
  for (int j = 0; j < 8; ++j) hi[j] = (_Float16)xs[j];
}
__device__ __forceinline__ void gll16(const void* g, void* l) {
  __builtin_amdgcn_global_load_lds(
      (const __attribute__((address_space(1))) void*)g,
      (__attribute__((address_space(3))) void*)l, 16, 0, 0);
}

// ---- kw: W_U -> frag-ordered single-f16 image (coalesced source for kz) ----
__global__ __launch_bounds__(256) void kw(const float* __restrict__ WU,
                                          _Float16* __restrict__ wimg) {
  int blk = blockIdx.x;  // 32: h = blk>>3, dgrp = blk&7
  int t = threadIdx.x, ln = t & 63, ks = t >> 6;
  int h = blk >> 3, dgrp = blk & 7;
  int d = dgrp * 16 + (ln & 15), e = ks * 32 + (ln >> 4) * 8;
  const float* src = WU + ((size_t)h * Dn + d) * Dn + e;
  float xs[8];
  *(float4*)xs = *(const float4*)src;
  *(float4*)(xs + 4) = *(const float4*)(src + 4);
  half8 hi;
  cvt8h(xs, hi);
  size_t u = (size_t)((h * 8 + dgrp) * 4 + ks) * 512 + (size_t)ln * 8;
  *(half8*)(wimg + u) = hi;
}

// ---- kz: Z[bh][m][d] = sum_e X2[m,b,e] WU[h,d,e]. 64-row tiles, grid 2048.
// A staged via gll16 (coalesced, swizzled-source); frags from LDS; buffer
// re-aliased as zt after A-frag loads. 1-term f16. Single-f16 zimg. ----
__global__ __launch_bounds__(256, 3) void kz(const float* __restrict__ X2,
                                             const _Float16* __restrict__ wimg,
                                             _Float16* __restrict__ zimg) {
  __shared__ __align__(16) char Abuf[64 * 132 * 4];  // 33792 B: A[64][128] then zt[64][132]
  int orig = blockIdx.x;
  int blk = (orig & 7) * 256 + (orig >> 3);  // XCD swizzle (2048 = 8*256)
  int h = blk & 3, mt6 = (blk >> 2) & 7, b = blk >> 5;
  int t = threadIdx.x, ln = t & 63, wv = t >> 6;
  int rg = wv >> 1, cb = wv & 1;
  int R0 = rg * 32;  // local row base in 64-row tile
  int eo = (ln >> 4) * 8;

  // ---- stage A: X2 tile rows [mt6*64, +64), f32, linear LDS [64][128],
  // source bytes pre-swizzled with u ^ ((r&7)<<4) (involution, rule #21)
#pragma unroll
  for (int p = 0; p < 8; ++p) {
    int r0 = wv * 16 + p * 2;          // wave-uniform row pair
    int r = r0 + (ln >> 5);            // per-lane row
    int u = (ln & 31) * 16;            // byte-in-row (dest)
    int su = u ^ ((r & 7) << 4);       // swizzled source byte
    const float* src = X2 + ((size_t)(mt6 * 64 + r) * Bn + b) * Dn + (su >> 2);
    gll16(src, Abuf + r0 * 512);
  }
  __syncthreads();  // A staged

  // ---- A frags from LDS (swizzled reads, ~2-way banks) -> registers
  half8 ahf[2][4];
#pragma unroll
  for (int mr = 0; mr < 2; ++mr) {
    int r = R0 + mr * 16 + (ln & 15);
    int swz = (r & 7) << 4;
#pragma unroll
    for (int ks = 0; ks < 4; ++ks) {
      int eb = (ks * 32 + eo) * 4;
      float xs[8];
      *(float4*)xs = *(const float4*)(Abuf + r * 512 + (eb ^ swz));
      *(float4*)(xs + 4) = *(const float4*)(Abuf + r * 512 + ((eb + 16) ^ swz));
      cvt8h(xs, ahf[mr][ks]);
    }
  }
  __syncthreads();  // all waves done reading A; buffer free for zt

  float* zt = (float*)Abuf;  // [64][132]
  const f32x4 fz = {0.f, 0.f, 0.f, 0.f};
#pragma unroll
  for (int ph = 0; ph < 2; ++ph) {  // d cols = cb*64 + ph*32
    f32x4 acc[2][2];
#pragma unroll
    for (int i = 0; i < 2; ++i) {
      acc[i][0] = fz;
      acc[i][1] = fz;
    }
    int dg0 = cb * 4 + ph * 2;
#pragma unroll
    for (int ks = 0; ks < 4; ++ks) {
      const _Float16* ub =
          wimg + (size_t)((h * 8 + dg0) * 4 + ks) * 512 + (size_t)ln * 8;
      half8 b0 = *(const half8*)ub;
      half8 b1 = *(const half8*)(ub + 2048);  // next dgrp unit
#pragma unroll
      for (int mr = 0; mr < 2; ++mr) {
        acc[mr][0] = __builtin_amdgcn_mfma_f32_16x16x32_f16(ahf[mr][ks], b0, acc[mr][0], 0, 0, 0);
        acc[mr][1] = __builtin_amdgcn_mfma_f32_16x16x32_f16(ahf[mr][ks], b1, acc[mr][1], 0, 0, 0);
      }
    }
#pragma unroll
    for (int mr = 0; mr < 2; ++mr) {
      int rb = R0 + mr * 16 + (ln >> 4) * 4;
#pragma unroll
      for (int nr = 0; nr < 2; ++nr) {
        int d = cb * 64 + ph * 32 + nr * 16 + (ln & 15);
#pragma unroll
        for (int j = 0; j < 4; ++j) zt[(rb + j) * 132 + d] = acc[mr][nr][j];
      }
    }
  }
  __syncthreads();
  // epilogue: zt -> single-f16 frag-ordered zimg units (16: 4 mgrp x 4 ks)
  int bh = b * 4 + h;
#pragma unroll
  for (int p = 0; p < 4; ++p) {
    int u = p * 4 + wv;  // mgl = u>>2, ksu = u&3
    int r = (u >> 2) * 16 + (ln & 15);
    int d = (u & 3) * 32 + eo;
    float xs[8];
    *(float4*)xs = *(const float4*)(zt + r * 132 + d);
    *(float4*)(xs + 4) = *(const float4*)(zt + r * 132 + d + 4);
    half8 hi;
    cvt8h(xs, hi);
    size_t ub = (((size_t)bh * 32 + mt6 * 4 + (u >> 2)) * 4 + (u & 3)) * 512 +
                (size_t)ln * 8;
    *(half8*)(zimg + ub) = hi;
  }
}

// ---- k1: per (b,h,rowhalf): 4 waves x 64 rows = 256 rows, ALL 512 cols.
// f16 1-term; 64-col chunks (8 phases x 64 MFMA), 16KB stage, gll dbuf. ----
__global__ __launch_bounds__(256, 2) void k1(const float* __restrict__ X1,
                                             const _Float16* __restrict__ zimg,
                                             const int* __restrict__ raw1,
                                             const int* __restrict__ raw2,
                                             float* __restrict__ s1,
                                             float* __restrict__ s2pp) {
  __shared__ __align__(16) char Bbuf[2][16384];
  __shared__ float m1f[256];
  __shared__ float m2f[512];
  __shared__ float cmbuf[4][512];

  int orig = blockIdx.x;
  int blk = (orig & 7) * 64 + (orig >> 3);  // XCD swizzle (512 = 8*64)
  int rh = blk & 1, h = (blk >> 1) & 3, b = blk >> 3;
  int bh = b * 4 + h;
  int t = threadIdx.x, ln = t & 63, wv = t >> 6;  // wv 0..3
  int R0 = rh * 256 + wv * 64;                    // global row base

  m1f[t] = (raw1[(size_t)(rh * 256 + t) * Bn + b] == 0) ? 1.0e4f : 0.0f;
  for (int i = t; i < 512; i += 256)
    m2f[i] = (raw2[(size_t)i * Bn + b] == 0) ? 1.0e4f : 0.0f;

  // chunk c: cols c*64 (4 cg-units); 8192 halves (16KB) linear at
  // (bh*32 + c*4)*2048. Per wave: 4 gll16 (unit wv + p*4).
#define STAGE(bb, c_)                                                    \
  {                                                                      \
    size_t ub = ((size_t)bh * 32 + (c_)*4) * 2048;                       \
    _Pragma("unroll") for (int p = 0; p < 4; ++p) {                      \
      gll16(zimg + ub + (size_t)(wv + p * 4) * 512 + (size_t)ln * 8,     \
            Bbuf[bb] + (wv + p * 4) * 1024);                             \
    }                                                                    \
  }

  STAGE(0, 0);

  // A resident: rows R0 + mr*16 + (ln&15), k = ks*32 + (ln>>4)*8, single f16
  half8 ahf[4][4];
  {
    int eo = (ln >> 4) * 8;
#pragma unroll
    for (int mr = 0; mr < 4; ++mr) {
      const float* rsrc =
          X1 + ((size_t)(R0 + mr * 16 + (ln & 15)) * Bn + b) * Dn + eo;
#pragma unroll
      for (int ks = 0; ks < 4; ++ks) {
        float xs[8];
        *(float4*)xs = *(const float4*)(rsrc + ks * 32);
        *(float4*)(xs + 4) = *(const float4*)(rsrc + ks * 32 + 4);
        cvt8h(xs, ahf[mr][ks]);
      }
    }
  }
  __syncthreads();  // stage(0) landed + masks ready

  float msub1[4][4];
#pragma unroll
  for (int mr = 0; mr < 4; ++mr)
#pragma unroll
    for (int j = 0; j < 4; ++j)
      msub1[mr][j] = m1f[wv * 64 + mr * 16 + (ln >> 4) * 4 + j];

  float rmrun[4][4];
#pragma unroll
  for (int i = 0; i < 4; ++i)
#pragma unroll
    for (int j = 0; j < 4; ++j) rmrun[i][j] = -3.0e38f;

  const f32x4 fz = {0.f, 0.f, 0.f, 0.f};
  int cur = 0;
  for (int c = 0; c < 8; ++c) {  // cols = c*64 .. +64
    if (c < 7) STAGE(cur ^ 1, c + 1);  // issue-early; ages under compute

    f32x4 acc[4][4];
#pragma unroll
    for (int i = 0; i < 4; ++i)
#pragma unroll
      for (int n = 0; n < 4; ++n) acc[i][n] = fz;
#pragma unroll
    for (int ks = 0; ks < 4; ++ks) {
      const char* base = Bbuf[cur] + ks * 1024 + ln * 16;
      half8 b0 = *(const half8*)base;
      half8 b1 = *(const half8*)(base + 4096);
      half8 b2 = *(const half8*)(base + 8192);
      half8 b3 = *(const half8*)(base + 12288);
#pragma unroll
      for (int mr = 0; mr < 4; ++mr) {
        acc[mr][0] = __builtin_amdgcn_mfma_f32_16x16x32_f16(ahf[mr][ks], b0, acc[mr][0], 0, 0, 0);
        acc[mr][1] = __builtin_amdgcn_mfma_f32_16x16x32_f16(ahf[mr][ks], b1, acc[mr][1], 0, 0, 0);
        acc[mr][2] = __builtin_amdgcn_mfma_f32_16x16x32_f16(ahf[mr][ks], b2, acc[mr][2], 0, 0, 0);
        acc[mr][3] = __builtin_amdgcn_mfma_f32_16x16x32_f16(ahf[mr][ks], b3, acc[mr][3], 0, 0, 0);
      }
    }
    // masked reductions
    float ms[4];
#pragma unroll
    for (int nr = 0; nr < 4; ++nr) ms[nr] = m2f[c * 64 + nr * 16 + (ln & 15)];
#pragma unroll
    for (int mr = 0; mr < 4; ++mr)
#pragma unroll
      for (int j = 0; j < 4; ++j) {
        float cc = fmaxf(fmaxf(acc[mr][0][j] - ms[0], acc[mr][1][j] - ms[1]),
                         fmaxf(acc[mr][2][j] - ms[2], acc[mr][3][j] - ms[3]));
        rmrun[mr][j] = fmaxf(rmrun[mr][j], cc);
      }
#pragma unroll
    for (int nr = 0; nr < 4; ++nr) {
      float v = -3.0e38f;
#pragma unroll
      for (int mr = 0; mr < 4; ++mr)
#pragma unroll
        for (int j = 0; j < 4; ++j) v = fmaxf(v, acc[mr][nr][j] - msub1[mr][j]);
      v = fmaxf(v, __shfl_xor(v, 16));
      v = fmaxf(v, __shfl_xor(v, 32));
      if (ln < 16) cmbuf[wv][c * 64 + nr * 16 + ln] = v;
    }
    __syncthreads();  // buf[cur] reads done; stage(cur^1) landed
    cur ^= 1;
  }
#undef STAGE

  // rowmax cross-lane + write (complete: all 512 cols seen)
#pragma unroll
  for (int off = 1; off < 16; off <<= 1)
#pragma unroll
    for (int mr = 0; mr < 4; ++mr)
#pragma unroll
      for (int j = 0; j < 4; ++j)
        rmrun[mr][j] = fmaxf(rmrun[mr][j], __shfl_xor(rmrun[mr][j], off));
  if ((ln & 15) == 0) {
    float* dst = s1 + (size_t)bh * 512 + R0 + (ln >> 4) * 4;
#pragma unroll
    for (int mr = 0; mr < 4; ++mr)
#pragma unroll
      for (int j = 0; j < 4; ++j) dst[mr * 16 + j] = rmrun[mr][j];
  }
  // colmax combine across 4 waves (partial: this rowhalf's 256 rows)
  for (int i = t; i < 512; i += 256) {
    float v = fmaxf(fmaxf(cmbuf[0][i], cmbuf[1][i]),
                    fmaxf(cmbuf[2][i], cmbuf[3][i]));
    s2pp[((size_t)bh * 2 + rh) * 512 + i] = v;
  }
}

// ---- k2: (side,b,lq): wave h = tanh+softmax; partial readout over l-quarter
__global__ __launch_bounds__(256) void k2(const float* __restrict__ s1,
                                          const float* __restrict__ s2pp,
                                          const float* __restrict__ X1,
                                          const float* __restrict__ X2,
                                          float* __restrict__ out,
                                          float* __restrict__ rws4) {
  __shared__ float aL[4][512];
  __shared__ f32x4 redv[4][8][32];
  int blk = blockIdx.x;  // 512
  int side = blk >> 8, b = (blk >> 2) & 63, lq = blk & 3;
  int t = threadIdx.x, ln = t & 63, h = t >> 6;
  int bh = b * 4 + h;
  int base = ln * 8;

  float vals[8];
  if (side == 0) {
    const float* p = s1 + (size_t)bh * 512 + base;
    float4 va = *(const float4*)p;
    float4 vb = *(const float4*)(p + 4);
    vals[0] = va.x; vals[1] = va.y; vals[2] = va.z; vals[3] = va.w;
    vals[4] = vb.x; vals[5] = vb.y; vals[6] = vb.z; vals[7] = vb.w;
  } else {
    const float* p0 = s2pp + (size_t)bh * 1024 + base;
    float4 va0 = *(const float4*)p0;
    float4 va1 = *(const float4*)(p0 + 4);
    float4 vb0 = *(const float4*)(p0 + 512);
    float4 vb1 = *(const float4*)(p0 + 516);
    vals[0] = fmaxf(va0.x, vb0.x); vals[1] = fmaxf(va0.y, vb0.y);
    vals[2] = fmaxf(va0.z, vb0.z); vals[3] = fmaxf(va0.w, vb0.w);
    vals[4] = fmaxf(va1.x, vb1.x); vals[5] = fmaxf(va1.y, vb1.y);
    vals[6] = fmaxf(va1.z, vb1.z); vals[7] = fmaxf(va1.w, vb1.w);
  }
#pragma unroll
  for (int q = 0; q < 8; ++q) vals[q] = tanhf(vals[q]);
  float mx = vals[0];
#pragma unroll
  for (int q = 1; q < 8; ++q) mx = fmaxf(mx, vals[q]);
#pragma unroll
  for (int off = 1; off < 64; off <<= 1) mx = fmaxf(mx, __shfl_xor(mx, off));
  float s = 0.0f;
#pragma unroll
  for (int q = 0; q < 8; ++q) {
    vals[q] = expf(vals[q] - mx);
    s += vals[q];
  }
#pragma unroll
  for (int off = 1; off < 64; off <<= 1) s += __shfl_xor(s, off);
  float inv = 1.0f / s;
#pragma unroll
  for (int q = 0; q < 8; ++q) vals[q] *= inv;

  if (lq == 0) {
    int aoff = (side == 0 ? 16384 : 147456) + bh * 512 + base;
    *(float4*)(out + aoff) = make_float4(vals[0], vals[1], vals[2], vals[3]);
    *(float4*)(out + aoff + 4) = make_float4(vals[4], vals[5], vals[6], vals[7]);
  }
  *(float4*)(&aL[h][base]) = make_float4(vals[0], vals[1], vals[2], vals[3]);
  *(float4*)(&aL[h][base + 4]) = make_float4(vals[4], vals[5], vals[6], vals[7]);
  __syncthreads();

  // partial readout over l in [lq*128, +128)
  const float4* X4 = (const float4*)(side == 0 ? X1 : X2);
  int q = t & 31, lg = t >> 5;
  f32x4 av[4];
  const f32x4 fz = {0.f, 0.f, 0.f, 0.f};
#pragma unroll
  for (int hh = 0; hh < 4; ++hh) av[hh] = fz;
#pragma unroll 4
  for (int l = lq * 128 + lg; l < lq * 128 + 128; l += 8) {
    float4 xv = X4[((size_t)l * Bn + b) * 32 + q];
#pragma unroll
    for (int hh = 0; hh < 4; ++hh) {
      float w = aL[hh][l];
      av[hh][0] += w * xv.x;
      av[hh][1] += w * xv.y;
      av[hh][2] += w * xv.z;
      av[hh][3] += w * xv.w;
    }
  }
#pragma unroll
  for (int hh = 0; hh < 4; ++hh) redv[hh][lg][q] = av[hh];
  __syncthreads();
  if (t < 128) {
    int d = t;
#pragma unroll
    for (int hh = 0; hh < 4; ++hh) {
      float s2v = 0.0f;
#pragma unroll
      for (int g = 0; g < 8; ++g) s2v += ((const float*)&redv[hh][g][d >> 2])[d & 3];
      rws4[(((size_t)(side * 64 + b) * 4 + hh) * 4 + lq) * 128 + d] = s2v;
    }
  }
}

// ---- k3: combine hops (sums lq partials) ----
__global__ __launch_bounds__(128) void k3(const float* __restrict__ rws4,
                                          const float* __restrict__ Wipm,
                                          float* __restrict__ out) {
  int b = blockIdx.x, t = threadIdx.x;  // t = d
  __shared__ float r2l[4][128];
  __shared__ float tsum[2][4];
  float r1h[4], r2h[4];
#pragma unroll
  for (int h = 0; h < 4; ++h) {
    float a0 = 0.f, a1 = 0.f;
#pragma unroll
    for (int lq = 0; lq < 4; ++lq) {
      a0 += rws4[(((size_t)b * 4 + h) * 4 + lq) * 128 + t];
      a1 += rws4[(((size_t)(64 + b) * 4 + h) * 4 + lq) * 128 + t];
    }
    r1h[h] = a0;
    r2h[h] = a1;
    r2l[h][t] = a1;
  }
  __syncthreads();
  float p[4] = {0, 0, 0, 0};
  for (int e = 0; e < 128; ++e) {
    float w = Wipm[t * 128 + e];
#pragma unroll
    for (int h = 0; h < 4; ++h) p[h] += w * r2l[h][e];
  }
#pragma unroll
  for (int h = 0; h < 4; ++h) p[h] *= r1h[h];
#pragma unroll
  for (int off = 1; off < 64; off <<= 1)
#pragma unroll
    for (int h = 0; h < 4; ++h) p[h] += __shfl_xor(p[h], off);
  if ((t & 63) == 0)
#pragma unroll
    for (int h = 0; h < 4; ++h) tsum[t >> 6][h] = p[h];
  __syncthreads();
  float ad[4], mx = -3.0e38f;
#pragma unroll
  for (int h = 0; h < 4; ++h) {
    float v = tanhf(tsum[0][h] + tsum[1][h]);
    ad[h] = v;
    mx = fmaxf(mx, v);
  }
  float s = 0.0f;
#pragma unroll
  for (int h = 0; h < 4; ++h) { ad[h] = expf(ad[h] - mx); s += ad[h]; }
  float inv = 1.0f / s;
#pragma unroll
  for (int h = 0; h < 4; ++h) ad[h] *= inv;
  if (t < 4) out[278528 + b * 4 + t] = ad[t];
  float f1 = 0.0f, f2 = 0.0f;
#pragma unroll
  for (int h = 0; h < 4; ++h) { f1 += ad[h] * r1h[h]; f2 += ad[h] * r2h[h]; }
  out[b * 128 + t] = f1;
  out[8192 + b * 128 + t] = f2;
}

extern "C" void kernel_launch(void* const* d_in, const int* in_sizes, int n_in,
                              void* d_out, int out_size, void* d_ws,
                              size_t ws_size, hipStream_t stream) {
  (void)in_sizes; (void)n_in; (void)out_size; (void)ws_size;
  const float* x1 = (const float*)d_in[0];
  const float* x2 = (const float*)d_in[1];
  const int* raw1 = (const int*)d_in[2];
  const int* raw2 = (const int*)d_in[3];
  const float* wu = (const float*)d_in[4];
  const float* wipm = (const float*)d_in[5];
  float* out = (float*)d_out;
  char* w = (char*)d_ws;
  _Float16* zimg = (_Float16*)w;                 // 32 MiB (64 MiB slot)
  _Float16* wimg = (_Float16*)(w + 67108864);    // 128 KiB
  float* s1 = (float*)(w + 67633152);            // 512 KiB [bh][512]
  float* s2pp = (float*)(w + 68157440);          // 1 MiB [bh][rh][512]
  float* rws4 = (float*)(w + 69206016);          // 1 MiB

  kw<<<32, 256, 0, stream>>>(wu, wimg);
  kz<<<2048, 256, 0, stream>>>(x2, wimg, zimg);
  k1<<<512, 256, 0, stream>>>(x1, zimg, raw1, raw2, s1, s2pp);
  k2<<<512, 256, 0, stream>>>(s1, s2pp, x1, x2, out, rws4);
  k3<<<64, 128, 0, stream>>>(rws4, wipm, out);
}